// Round 5
// baseline (3211.209 us; speedup 1.0000x reference)
//
#include <hip/hip_runtime.h>
#include <cstdint>
#include <cstddef>

typedef __bf16 bf16x8 __attribute__((ext_vector_type(8)));
typedef float f32x4 __attribute__((ext_vector_type(4)));

#define HD 256
#define TLEN 1000
#define NSTEP 999

// ws layout (bf16 elements): W1R | W2R | W3R | W4R, fragment-ordered
#define W1R_OFF 0
#define W2R_OFF 16384
#define W3R_OFF 81920
#define W4R_OFF 147456
#define WS_ELEMS 151552

__device__ __forceinline__ void wg_barrier() {
  // LDS-only drain + barrier: do NOT force vmcnt(0) like __syncthreads does,
  // so z-prefetch / out-stores stay in flight across layer barriers.
  asm volatile("s_waitcnt lgkmcnt(0)\n\ts_barrier" ::: "memory");
}

__device__ __forceinline__ uint32_t pk2bf(float a, float b) {
#if __has_builtin(__builtin_amdgcn_cvt_pk_bf16_f32)
  typedef __bf16 bf16x2 __attribute__((ext_vector_type(2)));
  union { bf16x2 v; uint32_t u; } cv;
  cv.v = __builtin_amdgcn_cvt_pk_bf16_f32(a, b);
  return cv.u;
#else
  union { __bf16 h[2]; uint32_t u; } cv;
  cv.h[0] = (__bf16)a; cv.h[1] = (__bf16)b;
  return cv.u;
#endif
}

__device__ __forceinline__ float elu(float v) {
  return v > 0.f ? v : (__expf(v) - 1.0f);
}

// Repack fp32 weights -> bf16 MFMA A-fragments in ws (runs every launch).
__global__ void prep_weights(const float* __restrict__ W1, const float* __restrict__ b1,
                             const float* __restrict__ W2, const float* __restrict__ W3,
                             const float* __restrict__ W4, __bf16* __restrict__ ws) {
  int tid = blockIdx.x * blockDim.x + threadIdx.x;
  if (tid >= WS_ELEMS) return;
  float val = 0.0f;
  if (tid < W2R_OFF) {                       // W1R: 8w x 2kb x 2tt x 64lane x 8j
    int t = tid;
    int j = t & 7, lane = (t >> 3) & 63, tt = (t >> 9) & 1, kb = (t >> 10) & 1, w = (t >> 11) & 7;
    int k = kb * 32 + ((lane >> 4) * 8) + j;
    int n = w * 32 + tt * 16 + (lane & 15);
    if (k < 48) val = W1[k * HD + n];
    else if (k == 48) val = b1[n];           // bias folded via constant-1 input at k=48
  } else if (tid < W3R_OFF) {                // W2R: 8w x 8kb x 2tt x 64 x 8
    int t = tid - W2R_OFF;
    int j = t & 7, lane = (t >> 3) & 63, tt = (t >> 9) & 1, kb = (t >> 10) & 7, w = (t >> 13) & 7;
    int k = kb * 32 + ((lane >> 4) * 8) + j;
    int n = w * 32 + tt * 16 + (lane & 15);
    val = W2[k * HD + n];
  } else if (tid < W4R_OFF) {                // W3R
    int t = tid - W3R_OFF;
    int j = t & 7, lane = (t >> 3) & 63, tt = (t >> 9) & 1, kb = (t >> 10) & 7, w = (t >> 13) & 7;
    int k = kb * 32 + ((lane >> 4) * 8) + j;
    int n = w * 32 + tt * 16 + (lane & 15);
    val = W3[k * HD + n];
  } else {                                   // W4R: 8kb x 64 x 8, N padded 8->16 with zeros
    int t = tid - W4R_OFF;
    int j = t & 7, lane = (t >> 3) & 63, kb = (t >> 9) & 7;
    int k = kb * 32 + ((lane >> 4) * 8) + j;
    int n = lane & 15;
    val = (n < 8) ? W4[k * 8 + n] : 0.0f;
  }
  ws[tid] = (__bf16)val;
}

// 8 waves x 32 hidden cols, tile 16 (all-live), 2 waves/SIMD.
// 3 barriers/step: reduce done via ds_add_f32 into facc; x-advance computed
// inline by consumers; wave 0 persists x_prev/out during P2; wave 2 pre-packs z.
__global__ __launch_bounds__(512, 2) void ode_main(
    const float* __restrict__ t_g, const float* __restrict__ x_g,
    const float* __restrict__ z_g, const float* __restrict__ ev_g,
    const float* __restrict__ zj_g, const float* __restrict__ b2_g,
    const float* __restrict__ b3_g, const float* __restrict__ b4_g,
    const __bf16* __restrict__ ws, float* __restrict__ out) {
  __shared__ __align__(16) __bf16 h_a[16 * 264];   // row 528B
  __shared__ __align__(16) __bf16 h_b[16 * 264];
  __shared__ __align__(16) float x_prev[16 * 12];  // stride 12 f32 (48B)
  __shared__ __align__(16) float facc[16 * 12];    // layer-4 accum (seed b4)
  __shared__ __align__(16) __bf16 zpk[16 * 8];     // packed z_eff (16B rows)
  __shared__ __align__(16) __bf16 zdpk[16 * 8];    // packed z_eff - z0
  __shared__ __align__(16) float x0s[16 * 12];
  __shared__ __align__(16) float z0s[16 * 12];
  __shared__ __align__(16) float zjs[16 * 12];
  __shared__ float evs[16];

  const int tid  = threadIdx.x;
  const int lane = tid & 63;
  const int wid  = tid >> 6;     // 8 waves; wave w owns hidden cols [32w, 32w+32)
  const int bcol = lane & 15;    // batch column in MFMA B/C layout
  const int q    = lane >> 4;    // quad
  const int b0   = blockIdx.x * 16;

  // ---- stage per-batch constants ----
  if (tid < 128) {
    int m = tid >> 3, d = tid & 7;
    size_t gb = (size_t)(b0 + m);
    float x0 = x_g[gb * (TLEN * 8) + d];
    float z0 = z_g[gb * (TLEN * 8) + d];
    float zj = zj_g[gb * 8 + d];
    float ev = ev_g[gb];
    x0s[m * 12 + d] = x0;
    z0s[m * 12 + d] = z0;
    zjs[m * 12 + d] = zj;
    x_prev[m * 12 + d] = x0;
    facc[m * 12 + d] = 0.f;                  // dtp=0 at iter 0 -> value unused, but keep finite
    float t0 = t_g[0];
    float ze = (t0 >= ev) ? zj : z0;         // z_eff for step 0
    zpk[m * 8 + d]  = (__bf16)ze;
    zdpk[m * 8 + d] = (__bf16)(ze - z0);
    out[gb * (TLEN * 8) + d] = x0;           // sol[:,0] = x0
    if (d == 0) evs[m] = ev;
  }
  __syncthreads();

  // ---- resident weight fragments (A-operand layout) ----
  const bf16x8* wsv = (const bf16x8*)ws;
  bf16x8 w1f[2][2], w2f[8][2], w3f[8][2];
#pragma unroll
  for (int kb = 0; kb < 2; ++kb)
#pragma unroll
    for (int tt = 0; tt < 2; ++tt)
      w1f[kb][tt] = wsv[(W1R_OFF / 8) + ((wid * 2 + kb) * 2 + tt) * 64 + lane];
#pragma unroll
  for (int kb = 0; kb < 8; ++kb)
#pragma unroll
    for (int tt = 0; tt < 2; ++tt) {
      w2f[kb][tt] = wsv[(W2R_OFF / 8) + ((wid * 8 + kb) * 2 + tt) * 64 + lane];
      w3f[kb][tt] = wsv[(W3R_OFF / 8) + ((wid * 8 + kb) * 2 + tt) * 64 + lane];
    }
  bf16x8 w4f = wsv[(W4R_OFF / 8) + wid * 64 + lane];  // k in [32*wid, 32*wid+32)

  // biases as C-init: lane's 4 C rows are hidden n = wid*32 + tt*16 + q*4 + e
  f32x4 b2v[2], b3v[2];
#pragma unroll
  for (int tt = 0; tt < 2; ++tt) {
    int n0 = wid * 32 + tt * 16 + q * 4;
    b2v[tt] = *(const f32x4*)(b2_g + n0);
    b3v[tt] = *(const f32x4*)(b3_g + n0);
  }
  // wave-0 personals (x persist + out store + facc reseed), lanes q<2
  f32x4 b4q = {0.f, 0.f, 0.f, 0.f};
  if (wid == 0 && q < 2) b4q = *(const f32x4*)(b4_g + q * 4);

  // wave-2 personals (z producer): lane -> (m1 = lane>>2, d0..d0+1)
  const int m1 = lane >> 2;
  const int d0 = (lane & 3) * 2;
  float2 zjf = make_float2(0.f, 0.f), z0f = make_float2(0.f, 0.f);
  float ev1 = 0.f;
  if (wid == 2) {
    zjf.x = zjs[m1 * 12 + d0];  zjf.y = zjs[m1 * 12 + d0 + 1];
    z0f.x = z0s[m1 * 12 + d0];  z0f.y = z0s[m1 * 12 + d0 + 1];
    ev1 = evs[m1];
  }

  // layer-1 per-lane B-frag constants (quad q supplies k = q*8+j for kb0, +32 for kb1):
  // kb0: q0 x0 | q1 z0 | q2 x-x0 | q3 z-z0 ; kb1: q0 x | q1 z | q2 one@k48 | q3 zero
  f32x4 sub0, sub1;
  bf16x8 a0c;
  {
    const float* base = ((q & 1) ? z0s : x0s) + bcol * 12;
    f32x4 r0 = *(const f32x4*)(base);
    f32x4 r1 = *(const f32x4*)(base + 4);
    sub0 = r0; sub1 = r1;
    union { uint32_t u[4]; bf16x8 v; } cv;
    cv.u[0] = pk2bf(r0[0], r0[1]); cv.u[1] = pk2bf(r0[2], r0[3]);
    cv.u[2] = pk2bf(r1[0], r1[1]); cv.u[3] = pk2bf(r1[2], r1[3]);
    a0c = cv.v;
  }
  bf16x8 zf;
#pragma unroll
  for (int e = 0; e < 8; ++e) zf[e] = (__bf16)0.f;
  bf16x8 k48f = zf;
  k48f[0] = (__bf16)1.0f;

  __syncthreads();

  float tcur = t_g[0];
  float dtp = 0.f;   // dt of previous step (0 => x_i = x_prev at iter 0)

  auto layer = [&](const __bf16* src, __bf16* dst, const bf16x8 (*wf)[2], const f32x4* bv) {
    bf16x8 bfr[8];
    const bf16x8* hp = (const bf16x8*)src;
#pragma unroll
    for (int kb = 0; kb < 8; ++kb) bfr[kb] = hp[bcol * 33 + kb * 4 + q];  // ds_read_b128 x8
#pragma unroll
    for (int tt = 0; tt < 2; ++tt) {
      f32x4 cA = bv[tt];
      f32x4 cB = {0.f, 0.f, 0.f, 0.f};
#pragma unroll
      for (int kb = 0; kb < 4; ++kb) {
        cA = __builtin_amdgcn_mfma_f32_16x16x32_bf16(wf[kb][tt], bfr[kb], cA, 0, 0, 0);
        cB = __builtin_amdgcn_mfma_f32_16x16x32_bf16(wf[kb + 4][tt], bfr[kb + 4], cB, 0, 0, 0);
      }
      union { uint32_t u[2]; unsigned long long ull; } o;
      o.u[0] = pk2bf(elu(cA[0] + cB[0]), elu(cA[1] + cB[1]));
      o.u[1] = pk2bf(elu(cA[2] + cB[2]), elu(cA[3] + cB[3]));
      *(unsigned long long*)(dst + bcol * 264 + wid * 32 + tt * 16 + q * 4) = o.ull;
    }
  };

#pragma unroll 1
  for (int i = 0; i < NSTEP; ++i) {
    float tn = t_g[i + 1];
    float2 zpre = make_float2(0.f, 0.f);
    if (wid == 2)  // prefetch z[:, i+1]; consumed at end of P3
      zpre = *(const float2*)(z_g + ((size_t)(b0 + m1) * TLEN + (i + 1)) * 8 + d0);

    // ---- P1: layer 1; x_i reconstructed inline from x_prev + dtp*facc ----
    {
      bf16x8 f0, f1;
      if ((q & 1) == 0) {  // q0 / q2: need x_i = x_prev + dtp*facc (8 dims of bcol)
        const float* xb = x_prev + bcol * 12;
        const float* fb = facc + bcol * 12;
        f32x4 xpA = *(const f32x4*)(xb);
        f32x4 xpB = *(const f32x4*)(xb + 4);
        f32x4 fA = *(const f32x4*)(fb);
        f32x4 fB = *(const f32x4*)(fb + 4);
        float xc[8];
#pragma unroll
        for (int e = 0; e < 4; ++e) {
          xc[e] = xpA[e] + dtp * fA[e];
          xc[e + 4] = xpB[e] + dtp * fB[e];
        }
        union { uint32_t u[4]; bf16x8 v; } cv;
        if (q == 0) {
          cv.u[0] = pk2bf(xc[0], xc[1]); cv.u[1] = pk2bf(xc[2], xc[3]);
          cv.u[2] = pk2bf(xc[4], xc[5]); cv.u[3] = pk2bf(xc[6], xc[7]);
          f0 = a0c; f1 = cv.v;
        } else {
          cv.u[0] = pk2bf(xc[0] - sub0[0], xc[1] - sub0[1]);
          cv.u[1] = pk2bf(xc[2] - sub0[2], xc[3] - sub0[3]);
          cv.u[2] = pk2bf(xc[4] - sub1[0], xc[5] - sub1[1]);
          cv.u[3] = pk2bf(xc[6] - sub1[2], xc[7] - sub1[3]);
          f0 = cv.v; f1 = k48f;
        }
      } else {             // q1 / q3: packed z reads
        const __bf16* zb = ((q == 1) ? zpk : zdpk) + bcol * 8;
        bf16x8 rd = *(const bf16x8*)zb;
        if (q == 1) { f0 = a0c; f1 = rd; }
        else        { f0 = rd;  f1 = zf; }
      }
#pragma unroll
      for (int tt = 0; tt < 2; ++tt) {
        f32x4 c = {0.f, 0.f, 0.f, 0.f};
        c = __builtin_amdgcn_mfma_f32_16x16x32_bf16(w1f[0][tt], f0, c, 0, 0, 0);
        c = __builtin_amdgcn_mfma_f32_16x16x32_bf16(w1f[1][tt], f1, c, 0, 0, 0);
        union { uint32_t u[2]; unsigned long long ull; } o;
        o.u[0] = pk2bf(elu(c[0]), elu(c[1]));
        o.u[1] = pk2bf(elu(c[2]), elu(c[3]));
        *(unsigned long long*)(h_a + bcol * 264 + wid * 32 + tt * 16 + q * 4) = o.ull;
      }
    }
    wg_barrier();  // B1

    // ---- P2: layer 2; wave 0 persists x_prev, stores out[i], reseeds facc ----
    layer(h_a, h_b, w2f, b2v);
    if (wid == 0 && q < 2) {
      float* xb = x_prev + bcol * 12 + q * 4;
      float* fb = facc + bcol * 12 + q * 4;
      f32x4 xp = *(const f32x4*)xb;
      f32x4 fv = *(const f32x4*)fb;
      f32x4 xn;
#pragma unroll
      for (int e = 0; e < 4; ++e) xn[e] = xp[e] + dtp * fv[e];
      *(f32x4*)xb = xn;                         // x_prev <- x_i
      *(f32x4*)fb = b4q;                        // facc seed = b4
      *(f32x4*)(out + (size_t)(b0 + bcol) * (TLEN * 8) + (size_t)i * 8 + q * 4) = xn;
    }
    wg_barrier();  // B2

    // ---- P3: layer 3 (h_b -> h_a), fused L4 partial + ds_add; wave 2 z-pack ----
    layer(h_b, h_a, w3f, b3v);
    {
      const bf16x8* hp = (const bf16x8*)h_a;
      bf16x8 h4 = hp[bcol * 33 + wid * 4 + q];  // own cols, same-wave ordering
      f32x4 c = {0.f, 0.f, 0.f, 0.f};
      c = __builtin_amdgcn_mfma_f32_16x16x32_bf16(w4f, h4, c, 0, 0, 0);
      if (q < 2) {
        float* fp = facc + bcol * 12 + q * 4;
#pragma unroll
        for (int e = 0; e < 4; ++e)
          __hip_atomic_fetch_add(fp + e, c[e], __ATOMIC_RELAXED, __HIP_MEMORY_SCOPE_WORKGROUP);
      }
    }
    if (wid == 2) {  // z_eff(i+1) packed for next P1
      bool jmp = (tn >= ev1);
      float za = jmp ? zjf.x : zpre.x;
      float zb = jmp ? zjf.y : zpre.y;
      *(uint32_t*)(zpk + m1 * 8 + d0)  = pk2bf(za, zb);
      *(uint32_t*)(zdpk + m1 * 8 + d0) = pk2bf(za - z0f.x, zb - z0f.y);
    }
    wg_barrier();  // B3

    dtp = tn - tcur;
    tcur = tn;
  }

  // final state x_999 = x_prev + dt_998 * facc  (facc final after last B3)
  if (wid == 0 && q < 2) {
    const float* xb = x_prev + bcol * 12 + q * 4;
    const float* fb = facc + bcol * 12 + q * 4;
    f32x4 xp = *(const f32x4*)xb;
    f32x4 fv = *(const f32x4*)fb;
    f32x4 xn;
#pragma unroll
    for (int e = 0; e < 4; ++e) xn[e] = xp[e] + dtp * fv[e];
    *(f32x4*)(out + (size_t)(b0 + bcol) * (TLEN * 8) + (size_t)NSTEP * 8 + q * 4) = xn;
  }
}

extern "C" void kernel_launch(void* const* d_in, const int* in_sizes, int n_in,
                              void* d_out, int out_size, void* d_ws, size_t ws_size,
                              hipStream_t stream) {
  const float* t  = (const float*)d_in[0];
  const float* x  = (const float*)d_in[1];
  const float* z  = (const float*)d_in[2];
  const float* ev = (const float*)d_in[3];
  const float* zj = (const float*)d_in[4];
  const float* W1 = (const float*)d_in[5];
  const float* b1 = (const float*)d_in[6];
  const float* W2 = (const float*)d_in[7];
  const float* b2 = (const float*)d_in[8];
  const float* W3 = (const float*)d_in[9];
  const float* b3 = (const float*)d_in[10];
  const float* W4 = (const float*)d_in[11];
  const float* b4 = (const float*)d_in[12];
  __bf16* ws = (__bf16*)d_ws;
  float* out = (float*)d_out;

  prep_weights<<<592, 256, 0, stream>>>(W1, b1, W2, W3, W4, ws);
  ode_main<<<64, 512, 0, stream>>>(t, x, z, ev, zj, b2, b3, b4, ws, out);
}

// Round 6
// 1916.765 us; speedup vs baseline: 1.6753x; 1.6753x over previous
//
#include <hip/hip_runtime.h>
#include <cstdint>
#include <cstddef>

typedef __bf16 bf16x8 __attribute__((ext_vector_type(8)));
typedef float f32x4 __attribute__((ext_vector_type(4)));

#define HD 256
#define TLEN 1000
#define NSTEP 999

// ws layout (bf16 elements): W1R | W2R | W3R | W4R, fragment-ordered
#define W1R_OFF 0
#define W2R_OFF 16384
#define W3R_OFF 81920
#define W4R_OFF 147456
#define WS_ELEMS 151552

__device__ __forceinline__ void wg_barrier() {
  // LDS-only drain + barrier: do NOT force vmcnt(0) like __syncthreads does,
  // so z-prefetch / out-stores stay in flight across layer barriers.
  asm volatile("s_waitcnt lgkmcnt(0)\n\ts_barrier" ::: "memory");
}

__device__ __forceinline__ uint32_t pk2bf(float a, float b) {
#if __has_builtin(__builtin_amdgcn_cvt_pk_bf16_f32)
  typedef __bf16 bf16x2 __attribute__((ext_vector_type(2)));
  union { bf16x2 v; uint32_t u; } cv;
  cv.v = __builtin_amdgcn_cvt_pk_bf16_f32(a, b);
  return cv.u;
#else
  union { __bf16 h[2]; uint32_t u; } cv;
  cv.h[0] = (__bf16)a; cv.h[1] = (__bf16)b;
  return cv.u;
#endif
}

__device__ __forceinline__ float elu(float v) {
  return v > 0.f ? v : (__expf(v) - 1.0f);
}

// Repack fp32 weights -> bf16 MFMA A-fragments in ws (runs every launch).
__global__ void prep_weights(const float* __restrict__ W1, const float* __restrict__ b1,
                             const float* __restrict__ W2, const float* __restrict__ W3,
                             const float* __restrict__ W4, __bf16* __restrict__ ws) {
  int tid = blockIdx.x * blockDim.x + threadIdx.x;
  if (tid >= WS_ELEMS) return;
  float val = 0.0f;
  if (tid < W2R_OFF) {                       // W1R: 8w x 2kb x 2tt x 64lane x 8j
    int t = tid;
    int j = t & 7, lane = (t >> 3) & 63, tt = (t >> 9) & 1, kb = (t >> 10) & 1, w = (t >> 11) & 7;
    int k = kb * 32 + ((lane >> 4) * 8) + j;
    int n = w * 32 + tt * 16 + (lane & 15);
    if (k < 48) val = W1[k * HD + n];
    else if (k == 48) val = b1[n];           // bias folded via constant-1 input at k=48
  } else if (tid < W3R_OFF) {                // W2R: 8w x 8kb x 2tt x 64 x 8
    int t = tid - W2R_OFF;
    int j = t & 7, lane = (t >> 3) & 63, tt = (t >> 9) & 1, kb = (t >> 10) & 7, w = (t >> 13) & 7;
    int k = kb * 32 + ((lane >> 4) * 8) + j;
    int n = w * 32 + tt * 16 + (lane & 15);
    val = W2[k * HD + n];
  } else if (tid < W4R_OFF) {                // W3R
    int t = tid - W3R_OFF;
    int j = t & 7, lane = (t >> 3) & 63, tt = (t >> 9) & 1, kb = (t >> 10) & 7, w = (t >> 13) & 7;
    int k = kb * 32 + ((lane >> 4) * 8) + j;
    int n = w * 32 + tt * 16 + (lane & 15);
    val = W3[k * HD + n];
  } else {                                   // W4R: 8kb x 64 x 8, N padded 8->16 with zeros
    int t = tid - W4R_OFF;
    int j = t & 7, lane = (t >> 3) & 63, kb = (t >> 9) & 7;
    int k = kb * 32 + ((lane >> 4) * 8) + j;
    int n = lane & 15;
    val = (n < 8) ? W4[k * 8 + n] : 0.0f;
  }
  ws[tid] = (__bf16)val;
}

// Round-3 skeleton (8 waves x 32 cols, tile 16, 2 waves/SIMD, 4 barriers,
// p4-partials + wave-0 reduce — NO atomics) + VALU diet:
//  - P1 inputs fully pre-packed to bf16 (xpk/xdpk by wave 0 in P4, zpk/zdpk by
//    wave 2): one ds_read_b128 per lane, zero cvt/sub in P1.
//  - packed bf16 cvt (v_cvt_pk_bf16_f32) on all ELU outputs.
//  - L2/L3 MFMA chains split 2x4 + merge add.
//  - x state lives in wave-0 registers (no x_cur LDS traffic).
__global__ __launch_bounds__(512, 2) void ode_main(
    const float* __restrict__ t_g, const float* __restrict__ x_g,
    const float* __restrict__ z_g, const float* __restrict__ ev_g,
    const float* __restrict__ zj_g, const float* __restrict__ b2_g,
    const float* __restrict__ b3_g, const float* __restrict__ b4_g,
    const __bf16* __restrict__ ws, float* __restrict__ out) {
  __shared__ __align__(16) __bf16 h_a[16 * 264];   // row 528B
  __shared__ __align__(16) __bf16 h_b[16 * 264];
  __shared__ __align__(16) float p4[8 * 16 * 8];   // layer-4 partials [wave][bcol][dim]
  __shared__ __align__(16) __bf16 xpk[16 * 8];     // packed x_i        (16B rows)
  __shared__ __align__(16) __bf16 xdpk[16 * 8];    // packed x_i - x0
  __shared__ __align__(16) __bf16 zpk[16 * 8];     // packed z_eff
  __shared__ __align__(16) __bf16 zdpk[16 * 8];    // packed z_eff - z0
  __shared__ __align__(16) float x0s[16 * 12];     // setup-only (a0c)
  __shared__ __align__(16) float z0s[16 * 12];     // setup-only (a0c)

  const int tid  = threadIdx.x;
  const int lane = tid & 63;
  const int wid  = tid >> 6;     // 8 waves; wave w owns hidden cols [32w, 32w+32)
  const int bcol = lane & 15;    // batch column in MFMA B/C layout
  const int q    = lane >> 4;    // quad
  const int b0   = blockIdx.x * 16;

  // pair-mapping used by wave 0 (x/out) and wave 2 (z): lane -> (mp, dp, dp+1)
  const int mp = lane >> 2;          // batch row 0..15
  const int dp = (lane & 3) * 2;     // dim pair base 0,2,4,6

  // ---- stage x0/z0 rows for a0c construction ----
  if (tid < 128) {
    int m = tid >> 3, d = tid & 7;
    size_t gb = (size_t)(b0 + m);
    x0s[m * 12 + d] = x_g[gb * (TLEN * 8) + d];
    z0s[m * 12 + d] = z_g[gb * (TLEN * 8) + d];
  }

  // ---- wave-0 personals: x state in registers; seed xpk/xdpk; out[0] ----
  float xr0 = 0.f, xr1 = 0.f, x00 = 0.f, x01 = 0.f, b4a = 0.f, b4b = 0.f;
  if (wid == 0) {
    size_t gb = (size_t)(b0 + mp);
    float2 x0p = *(const float2*)(x_g + gb * (TLEN * 8) + dp);
    xr0 = x00 = x0p.x;  xr1 = x01 = x0p.y;
    b4a = b4_g[dp];  b4b = b4_g[dp + 1];
    *(uint32_t*)(xpk + mp * 8 + dp)  = pk2bf(x0p.x, x0p.y);
    *(uint32_t*)(xdpk + mp * 8 + dp) = pk2bf(0.f, 0.f);
    *(float2*)(out + gb * (TLEN * 8) + dp) = x0p;   // sol[:,0] = x0
  }

  // ---- wave-2 personals: z constants; seed zpk/zdpk for step 0 ----
  float2 zjf = make_float2(0.f, 0.f), z0f = make_float2(0.f, 0.f);
  float ev1 = 0.f;
  if (wid == 2) {
    size_t gb = (size_t)(b0 + mp);
    z0f = *(const float2*)(z_g + gb * (TLEN * 8) + dp);
    zjf = *(const float2*)(zj_g + gb * 8 + dp);
    ev1 = ev_g[gb];
    float t0 = t_g[0];
    float za = (t0 >= ev1) ? zjf.x : z0f.x;
    float zb = (t0 >= ev1) ? zjf.y : z0f.y;
    *(uint32_t*)(zpk + mp * 8 + dp)  = pk2bf(za, zb);
    *(uint32_t*)(zdpk + mp * 8 + dp) = pk2bf(za - z0f.x, zb - z0f.y);
  }

  // ---- resident weight fragments (A-operand layout) ----
  const bf16x8* wsv = (const bf16x8*)ws;
  bf16x8 w1f[2][2], w2f[8][2], w3f[8][2];
#pragma unroll
  for (int kb = 0; kb < 2; ++kb)
#pragma unroll
    for (int tt = 0; tt < 2; ++tt)
      w1f[kb][tt] = wsv[(W1R_OFF / 8) + ((wid * 2 + kb) * 2 + tt) * 64 + lane];
#pragma unroll
  for (int kb = 0; kb < 8; ++kb)
#pragma unroll
    for (int tt = 0; tt < 2; ++tt) {
      w2f[kb][tt] = wsv[(W2R_OFF / 8) + ((wid * 8 + kb) * 2 + tt) * 64 + lane];
      w3f[kb][tt] = wsv[(W3R_OFF / 8) + ((wid * 8 + kb) * 2 + tt) * 64 + lane];
    }
  bf16x8 w4f = wsv[(W4R_OFF / 8) + wid * 64 + lane];  // k in [32*wid, 32*wid+32)

  // biases as C-init: lane's 4 C rows are hidden n = wid*32 + tt*16 + q*4 + e
  f32x4 b2v[2], b3v[2];
#pragma unroll
  for (int tt = 0; tt < 2; ++tt) {
    int n0 = wid * 32 + tt * 16 + q * 4;
    b2v[tt] = *(const f32x4*)(b2_g + n0);
    b3v[tt] = *(const f32x4*)(b3_g + n0);
  }

  __syncthreads();   // x0s/z0s + seeded packs visible

  // a0c: constant kb0 operand for q0 (x0 row) / q1 (z0 row); unused q2/q3
  bf16x8 a0c;
  {
    const float* base = ((q & 1) ? z0s : x0s) + bcol * 12;
    f32x4 r0 = *(const f32x4*)(base);
    f32x4 r1 = *(const f32x4*)(base + 4);
    union { uint32_t u[4]; bf16x8 v; } cv;
    cv.u[0] = pk2bf(r0[0], r0[1]); cv.u[1] = pk2bf(r0[2], r0[3]);
    cv.u[2] = pk2bf(r1[0], r1[1]); cv.u[3] = pk2bf(r1[2], r1[3]);
    a0c = cv.v;
  }
  bf16x8 zf;
#pragma unroll
  for (int e = 0; e < 8; ++e) zf[e] = (__bf16)0.f;
  bf16x8 k48f = zf;
  k48f[0] = (__bf16)1.0f;  // constant-1 input at padded k=48 -> adds b1

  float tcur = t_g[0];

  auto layer = [&](const __bf16* src, __bf16* dst, const bf16x8 (*wf)[2], const f32x4* bv) {
    bf16x8 bfr[8];
    const bf16x8* hp = (const bf16x8*)src;
#pragma unroll
    for (int kb = 0; kb < 8; ++kb) bfr[kb] = hp[bcol * 33 + kb * 4 + q];  // ds_read_b128 x8
#pragma unroll
    for (int tt = 0; tt < 2; ++tt) {
      f32x4 cA = bv[tt];
      f32x4 cB = {0.f, 0.f, 0.f, 0.f};
#pragma unroll
      for (int kb = 0; kb < 4; ++kb) {   // two 4-deep chains (shorter dep latency)
        cA = __builtin_amdgcn_mfma_f32_16x16x32_bf16(wf[kb][tt], bfr[kb], cA, 0, 0, 0);
        cB = __builtin_amdgcn_mfma_f32_16x16x32_bf16(wf[kb + 4][tt], bfr[kb + 4], cB, 0, 0, 0);
      }
      union { uint32_t u[2]; unsigned long long ull; } o;
      o.u[0] = pk2bf(elu(cA[0] + cB[0]), elu(cA[1] + cB[1]));
      o.u[1] = pk2bf(elu(cA[2] + cB[2]), elu(cA[3] + cB[3]));
      *(unsigned long long*)(dst + bcol * 264 + wid * 32 + tt * 16 + q * 4) = o.ull;
    }
  };

#pragma unroll 1
  for (int i = 0; i < NSTEP; ++i) {
    float tn = t_g[i + 1];
    float2 zpre = make_float2(0.f, 0.f);
    if (wid == 2)  // prefetch z[:, i+1]; consumed in P4 of this step
      zpre = *(const float2*)(z_g + ((size_t)(b0 + mp) * TLEN + (i + 1)) * 8 + dp);

    // ---- P1: layer 1 — all inputs pre-packed bf16, one b128 read per lane ----
    {
      const __bf16* src1 = (q == 0) ? xpk : (q == 1) ? zpk : (q == 2) ? xdpk : zdpk;
      bf16x8 rd = *(const bf16x8*)(src1 + bcol * 8);
      bf16x8 f0, f1;
      if (q < 2)      { f0 = a0c; f1 = rd; }            // k0-15 const | k32-47 current
      else if (q == 2){ f0 = rd;  f1 = k48f; }          // k16-23 x-x0 | k48 bias-one
      else            { f0 = rd;  f1 = zf; }            // k24-31 z-z0 | zero
#pragma unroll
      for (int tt = 0; tt < 2; ++tt) {
        f32x4 c = {0.f, 0.f, 0.f, 0.f};
        c = __builtin_amdgcn_mfma_f32_16x16x32_bf16(w1f[0][tt], f0, c, 0, 0, 0);
        c = __builtin_amdgcn_mfma_f32_16x16x32_bf16(w1f[1][tt], f1, c, 0, 0, 0);
        union { uint32_t u[2]; unsigned long long ull; } o;
        o.u[0] = pk2bf(elu(c[0]), elu(c[1]));
        o.u[1] = pk2bf(elu(c[2]), elu(c[3]));
        *(unsigned long long*)(h_a + bcol * 264 + wid * 32 + tt * 16 + q * 4) = o.ull;
      }
    }
    wg_barrier();  // B1
    layer(h_a, h_b, w2f, b2v);   // P2: layer 2
    wg_barrier();  // B2
    layer(h_b, h_a, w3f, b3v);   // P3: layer 3 (h3 -> h_a)

    // ---- P3b (fused, no barrier): layer-4 partial on OWN 32 columns ----
    {
      const bf16x8* hp = (const bf16x8*)h_a;
      bf16x8 h4 = hp[bcol * 33 + wid * 4 + q];  // own cols, same-wave ordering
      f32x4 c = {0.f, 0.f, 0.f, 0.f};
      c = __builtin_amdgcn_mfma_f32_16x16x32_bf16(w4f, h4, c, 0, 0, 0);
      if (q < 2)  // valid out rows n = q*4+e < 8
        *(f32x4*)(p4 + wid * 128 + bcol * 8 + q * 4) = c;
    }
    wg_barrier();  // B3

    // ---- P4: reduce + Euler + re-pack (wave 0); z_eff(i+1) pack (wave 2) ----
    float dt = tn - tcur;
    if (wid == 0) {
      float s0 = b4a, s1 = b4b;
#pragma unroll
      for (int j = 0; j < 8; ++j) {
        float2 pv = *(const float2*)(p4 + j * 128 + mp * 8 + dp);
        s0 += pv.x; s1 += pv.y;
      }
      xr0 += dt * s0;  xr1 += dt * s1;
      *(float2*)(out + (size_t)(b0 + mp) * (TLEN * 8) + (size_t)(i + 1) * 8 + dp) =
          make_float2(xr0, xr1);
      *(uint32_t*)(xpk + mp * 8 + dp)  = pk2bf(xr0, xr1);
      *(uint32_t*)(xdpk + mp * 8 + dp) = pk2bf(xr0 - x00, xr1 - x01);
    } else if (wid == 2) {
      bool jmp = (tn >= ev1);
      float za = jmp ? zjf.x : zpre.x;
      float zb = jmp ? zjf.y : zpre.y;
      *(uint32_t*)(zpk + mp * 8 + dp)  = pk2bf(za, zb);
      *(uint32_t*)(zdpk + mp * 8 + dp) = pk2bf(za - z0f.x, zb - z0f.y);
    }
    tcur = tn;
    wg_barrier();  // B4
  }
}

extern "C" void kernel_launch(void* const* d_in, const int* in_sizes, int n_in,
                              void* d_out, int out_size, void* d_ws, size_t ws_size,
                              hipStream_t stream) {
  const float* t  = (const float*)d_in[0];
  const float* x  = (const float*)d_in[1];
  const float* z  = (const float*)d_in[2];
  const float* ev = (const float*)d_in[3];
  const float* zj = (const float*)d_in[4];
  const float* W1 = (const float*)d_in[5];
  const float* b1 = (const float*)d_in[6];
  const float* W2 = (const float*)d_in[7];
  const float* b2 = (const float*)d_in[8];
  const float* W3 = (const float*)d_in[9];
  const float* b3 = (const float*)d_in[10];
  const float* W4 = (const float*)d_in[11];
  const float* b4 = (const float*)d_in[12];
  __bf16* ws = (__bf16*)d_ws;
  float* out = (float*)d_out;

  prep_weights<<<592, 256, 0, stream>>>(W1, b1, W2, W3, W4, ws);
  ode_main<<<64, 512, 0, stream>>>(t, x, z, ev, zj, b2, b3, b4, ws, out);
}